// Round 2
// baseline (305.188 us; speedup 1.0000x reference)
//
#include <hip/hip_runtime.h>

#define N_NODES 50000
#define N_EDGES 1600000
#define NPB     16
#define NCHAIN  16    // sub-chains per node: chain = e & 15
#define MSTR    164   // pool row stride (160 + 4 pad: breaks LDS bank conflict on A-frag reads; 16B-aligned rows)
#define EPSV    1e-8f

typedef float f32x4 __attribute__((ext_vector_type(4)));
typedef short s16x8 __attribute__((ext_vector_type(8)));

__device__ __forceinline__ float sigmoidf_(float x) { return 1.0f / (1.0f + __expf(-x)); }
// f32 -> bf16 bits, round-to-nearest-even
__device__ __forceinline__ short f2bf(float x) {
    unsigned u = __float_as_uint(x);
    unsigned r = (u + 0x7FFFu + ((u >> 16) & 1u)) >> 16;
    return (short)r;
}
__device__ __forceinline__ float bf2f(short h) {
    return __uint_as_float(((unsigned)(unsigned short)h) << 16);
}

// ---------------------------------------------------------------------------
// Prep: Dekker-split W_so into bf16 hi/lo, padded to 160 K-rows (rows >=153
// zeroed so the MFMA K-loop needs no bounds check).
// ---------------------------------------------------------------------------
__global__ __launch_bounds__(256) void prep_w_kernel(
    const float* __restrict__ W_so, short* __restrict__ Whi, short* __restrict__ Wlo) {
    int i = blockIdx.x * 256 + threadIdx.x;  // i = k*128 + o
    if (i >= 160 * 128) return;
    int k = i >> 7;
    float w = (k < 153) ? W_so[i] : 0.0f;
    short hh = f2bf(w);
    Whi[i] = hh;
    Wlo[i] = f2bf(w - bf2f(hh));
}

// ---------------------------------------------------------------------------
// Kernel 1: 16-way linked-list bucketing. 1 atomicExch + 1 coalesced store
// per edge = minimal fabric ops for a data-dependent scatter.
// ---------------------------------------------------------------------------
__global__ __launch_bounds__(256) void bucket_kernel(
    const int* __restrict__ row,
    int* __restrict__ head,
    int* __restrict__ nxt) {
    int e = blockIdx.x * 256 + threadIdx.x;
    if (e >= N_EDGES) return;
    int r = row[e];
    int prev = atomicExch(&head[r * NCHAIN + (e & (NCHAIN - 1))], e);
    nxt[e] = prev;
}

// ---------------------------------------------------------------------------
// Kernel 2: all per-node algebra. 16 nodes per 256-thread block.
// LDS diet for occupancy: 18.5 KB/block -> 8 blocks/CU (was 38.9 KB -> 4).
//  - chain/gate partial reduces via __shfl_xor (16 chains of a node are 16
//    consecutive lanes of one wave) instead of redL/tmpL LDS arrays
//  - sigL unions onto mergedL (dead after MFMA A-frag reads; barrier guards)
// __launch_bounds__(256,8) pins VGPR<=64 (occupancy cliff at 64).
// ---------------------------------------------------------------------------
__global__ __launch_bounds__(256, 8) void node_kernel(
    const float* __restrict__ s,
    const float* __restrict__ v,
    const float* __restrict__ frames,
    const float* __restrict__ W_vd,
    const float* __restrict__ W_vdf,
    const short* __restrict__ Whi,
    const short* __restrict__ Wlo,
    const float* __restrict__ b_so,
    const float* __restrict__ W_vu,
    const float* __restrict__ W_vosf,
    const float* __restrict__ b_vosf,
    const float* __restrict__ W_vuf,
    const int* __restrict__ head,
    const int* __restrict__ nxt,
    float* __restrict__ out0,
    float* __restrict__ out1)
{
    __shared__ __align__(16) float poolL[NPB][MSTR];  // phase<=2: merged rows; epilogue+: sigL[16][128]
    __shared__ float vL[NPB][48];
    __shared__ float vhL[NPB][3][16];
    __shared__ float FbarL[NPB][9];
    __shared__ float vdfL[NPB][9];
    __shared__ float gateL[NPB][12];

    float (*sigL)[128] = (float (*)[128])&poolL[0][0];

    const int t = threadIdx.x;
    const int base = blockIdx.x * NPB;
    const int nn = t >> 4, h = t & 15;
    const int n = base + nn;

    // ---- phase 0: issue head load first (latency overlaps staging), stage
    //      v,s; 256 walkers traverse the 16 sub-chains; butterfly reduce ----
    int e = head[(size_t)n * NCHAIN + h];

#pragma unroll
    for (int r = 0; r < 3; r++) vL[nn][h * 3 + r] = v[(size_t)n * 48 + h * 3 + r];
#pragma unroll
    for (int r = 0; r < 8; r++) poolL[nn][h * 8 + r] = s[(size_t)n * 128 + h * 8 + r];

    {
        float fs[10];
#pragma unroll
        for (int k = 0; k < 10; k++) fs[k] = 0.f;
        while (e >= 0) {
            int en = nxt[e];  // dependent load issues first; frame loads overlap it
            const float* f = frames + (size_t)e * 9;
#pragma unroll
            for (int k = 0; k < 9; k++) fs[k] += f[k];
            fs[9] += 1.0f;
            e = en;
        }
        // butterfly across the node's 16 lanes (contiguous within the wave)
#pragma unroll
        for (int m = 1; m < 16; m <<= 1) {
#pragma unroll
            for (int k = 0; k < 10; k++) fs[k] += __shfl_xor(fs[k], m);
        }
        if (h < 9) {
            float inv = 1.0f / fmaxf(fs[9], 1.0f);
            FbarL[nn][h] = fs[h] * inv;
        }
    }
    __syncthreads();

    // ---- phase 1b: vh, vnorm, vdf ----
    {
        float vh0 = 0.f, vh1 = 0.f, vh2 = 0.f;
#pragma unroll
        for (int i = 0; i < 16; i++) {
            float w = W_vd[i * 16 + h];
            vh0 += vL[nn][i * 3 + 0] * w;
            vh1 += vL[nn][i * 3 + 1] * w;
            vh2 += vL[nn][i * 3 + 2] * w;
        }
        vhL[nn][0][h] = vh0; vhL[nn][1][h] = vh1; vhL[nn][2][h] = vh2;
        poolL[nn][128 + h] = sqrtf(vh0 * vh0 + vh1 * vh1 + vh2 * vh2 + EPSV);
        if (h < 3) {
            int cc = h;
#pragma unroll
            for (int j = 0; j < 3; j++) {
                float a = 0.f;
#pragma unroll
                for (int i = 0; i < 16; i++) a += vL[nn][i * 3 + j] * W_vdf[i * 3 + cc];
                vdfL[nn][j * 3 + cc] = a;
            }
        }
    }
    __syncthreads();

    // ---- phase 1c: sh + zero-pad merged[144..163] ----
    {
        if (h < 9) {
            int c = h / 3, i = h % 3;
            float a = 0.f;
#pragma unroll
            for (int j = 0; j < 3; j++) a += FbarL[nn][i * 3 + j] * vdfL[nn][j * 3 + c];
            poolL[nn][144 + h] = a;
        } else {
            poolL[nn][144 + h] = 0.0f;  // 153..159
        }
        if (h < 4) poolL[nn][160 + h] = 0.0f;  // stride pad
    }
    __syncthreads();

    // ---- phase 2: C[16x128] = merged[16x160] @ W_so via split-bf16 MFMA ----
    // wave w handles o in [32w, 32w+32): two 16x16 tiles, K-loop 5x32.
    // A-frag: A[m=lane&15][k=quad*8+j]; B-frag: B[k=quad*8+j][n=lane&15];
    // C/D: col=lane&15, row=quad*4+reg (m89/m91/m120-verified layouts).
    {
        const int w = t >> 6;
        const int lane = t & 63;
        const int quad = lane >> 4;
        const int col = lane & 15;
        f32x4 acc[2];
        acc[0] = (f32x4){0.f, 0.f, 0.f, 0.f};
        acc[1] = (f32x4){0.f, 0.f, 0.f, 0.f};
#pragma unroll
        for (int kk = 0; kk < 5; kk++) {
            const int krow = kk * 32 + quad * 8;
            const float* ap = &poolL[col][krow];
            float4 a0v = *(const float4*)ap;
            float4 a1v = *(const float4*)(ap + 4);
            float av[8] = {a0v.x, a0v.y, a0v.z, a0v.w, a1v.x, a1v.y, a1v.z, a1v.w};
            s16x8 ahi, alo;
#pragma unroll
            for (int j = 0; j < 8; j++) {
                short hh = f2bf(av[j]);
                ahi[j] = hh;
                alo[j] = f2bf(av[j] - bf2f(hh));
            }
#pragma unroll
            for (int t0 = 0; t0 < 2; t0++) {
                int o = w * 32 + t0 * 16 + col;
                s16x8 bhi, blo;
#pragma unroll
                for (int j = 0; j < 8; j++) {
                    bhi[j] = Whi[(krow + j) * 128 + o];
                    blo[j] = Wlo[(krow + j) * 128 + o];
                }
                acc[t0] = __builtin_amdgcn_mfma_f32_16x16x32_bf16(ahi, bhi, acc[t0], 0, 0, 0);
                acc[t0] = __builtin_amdgcn_mfma_f32_16x16x32_bf16(ahi, blo, acc[t0], 0, 0, 0);
                acc[t0] = __builtin_amdgcn_mfma_f32_16x16x32_bf16(alo, bhi, acc[t0], 0, 0, 0);
            }
        }
        __syncthreads();  // all A-frag reads of poolL done -> safe to overlay sigL
        // epilogue: bias, relu -> out0, sigmoid -> sigL (overlaid on poolL)
#pragma unroll
        for (int t0 = 0; t0 < 2; t0++) {
            int o = w * 32 + t0 * 16 + col;
            float bso = b_so[o];
#pragma unroll
            for (int r = 0; r < 4; r++) {
                int nl = quad * 4 + r;
                float val = acc[t0][r] + bso;
                out0[(size_t)(base + nl) * 128 + o] = fmaxf(val, 0.0f);
                sigL[nl][o] = sigmoidf_(val);
            }
        }
    }
    __syncthreads();

    // ---- gate = sigmoid(sr) @ W_vosf + b_vosf : partials + shfl butterfly ----
    {
        const float* sp = &sigL[nn][h * 8];
        float4 s0 = *(const float4*)sp;
        float4 s1 = *(const float4*)(sp + 4);
        float sv[8] = {s0.x, s0.y, s0.z, s0.w, s1.x, s1.y, s1.z, s1.w};
        float p[9];
#pragma unroll
        for (int k = 0; k < 9; k++) p[k] = 0.f;
#pragma unroll
        for (int i = 0; i < 8; i++) {
            int o = h * 8 + i;
#pragma unroll
            for (int k = 0; k < 9; k++) p[k] += sv[i] * W_vosf[o * 9 + k];
        }
#pragma unroll
        for (int m = 1; m < 16; m <<= 1) {
#pragma unroll
            for (int k = 0; k < 9; k++) p[k] += __shfl_xor(p[k], m);
        }
        if (h < 9) gateL[nn][h] = p[h] + b_vosf[h];
    }
    __syncthreads();

    // ---- phase 3: vector path ----
    {
        int o = h;  // VO index
        float gv[9];
#pragma unroll
        for (int i = 0; i < 3; i++)
#pragma unroll
            for (int kk = 0; kk < 3; kk++) {
                float a = 0.f;
#pragma unroll
                for (int j = 0; j < 3; j++) a += gateL[nn][j * 3 + i] * FbarL[nn][j * 3 + kk];
                gv[i * 3 + kk] = a;
            }
        float gvr[3];
#pragma unroll
        for (int kk = 0; kk < 3; kk++) {
            float a = 0.f;
#pragma unroll
            for (int i = 0; i < 3; i++) a += gv[i * 3 + kk] * W_vuf[i * 16 + o];
            gvr[kk] = a;
        }
        float gn2 = sqrtf(gvr[0] * gvr[0] + gvr[1] * gvr[1] + gvr[2] * gvr[2] + EPSV);
        float sg = sigmoidf_(gn2);
#pragma unroll
        for (int c = 0; c < 3; c++) {
            float a = 0.f;
#pragma unroll
            for (int h2 = 0; h2 < 16; h2++) a += vhL[nn][c][h2] * W_vu[h2 * 16 + o];
            out1[(size_t)n * 48 + o * 3 + c] = a * sg;
        }
    }
}

extern "C" void kernel_launch(void* const* d_in, const int* in_sizes, int n_in,
                              void* d_out, int out_size, void* d_ws, size_t ws_size,
                              hipStream_t stream) {
    const float* s      = (const float*)d_in[0];
    const float* v      = (const float*)d_in[1];
    const float* frames = (const float*)d_in[2];
    const float* W_vd   = (const float*)d_in[3];
    const float* W_vdf  = (const float*)d_in[4];
    const float* W_so   = (const float*)d_in[5];
    const float* b_so   = (const float*)d_in[6];
    const float* W_vu   = (const float*)d_in[7];
    const float* W_vosf = (const float*)d_in[8];
    const float* b_vosf = (const float*)d_in[9];
    const float* W_vuf  = (const float*)d_in[10];
    const int* edge_index = (const int*)d_in[11];
    // d_in[12] = node_inputs (assumed truthy, per reference)

    // ws: head[50K*16 int] | next[1.6M int] | Whi[160*128 s16] | Wlo[160*128 s16]
    const size_t head_b = (size_t)N_NODES * NCHAIN * sizeof(int);  // 3.2 MB
    const size_t next_b = (size_t)N_EDGES * sizeof(int);           // 6.4 MB
    int*   head = (int*)d_ws;
    int*   nxt  = (int*)((char*)d_ws + head_b);
    short* Whi  = (short*)((char*)d_ws + head_b + next_b);
    short* Wlo  = Whi + 160 * 128;
    float* out0 = (float*)d_out;
    float* out1 = out0 + (size_t)N_NODES * 128;

    hipMemsetAsync(head, 0xFF, head_b, stream);  // head[n][c] = -1
    prep_w_kernel<<<(160 * 128 + 255) / 256, 256, 0, stream>>>(W_so, Whi, Wlo);
    bucket_kernel<<<(N_EDGES + 255) / 256, 256, 0, stream>>>(edge_index, head, nxt);
    node_kernel<<<N_NODES / NPB, 256, 0, stream>>>(
        s, v, frames, W_vd, W_vdf, Whi, Wlo, b_so, W_vu, W_vosf, b_vosf, W_vuf,
        head, nxt, out0, out1);
}

// Round 3
// 290.376 us; speedup vs baseline: 1.0510x; 1.0510x over previous
//
#include <hip/hip_runtime.h>

#define N_NODES 50000
#define N_EDGES 1600000
#define NPB     16
#define NCHAIN  16    // sub-chains per node: chain = e & 15
#define MSTR    164   // pool row stride (160 + 4 pad: breaks LDS bank conflict on A-frag reads; 16B-aligned rows)
#define EPSV    1e-8f

typedef float f32x4 __attribute__((ext_vector_type(4)));
typedef short s16x8 __attribute__((ext_vector_type(8)));

// 4-aligned 16B chunk for the frames gather (frames rows are 36B, only 4B-aligned)
struct f4u { float a, b, c, d; };

__device__ __forceinline__ float sigmoidf_(float x) { return 1.0f / (1.0f + __expf(-x)); }
// f32 -> bf16 bits, round-to-nearest-even
__device__ __forceinline__ short f2bf(float x) {
    unsigned u = __float_as_uint(x);
    unsigned r = (u + 0x7FFFu + ((u >> 16) & 1u)) >> 16;
    return (short)r;
}
__device__ __forceinline__ float bf2f(short h) {
    return __uint_as_float(((unsigned)(unsigned short)h) << 16);
}

// ---------------------------------------------------------------------------
// Prep: Dekker-split W_so into bf16 hi/lo, padded to 160 K-rows (rows >=153
// zeroed so the MFMA K-loop needs no bounds check).
// ---------------------------------------------------------------------------
__global__ __launch_bounds__(256) void prep_w_kernel(
    const float* __restrict__ W_so, short* __restrict__ Whi, short* __restrict__ Wlo) {
    int i = blockIdx.x * 256 + threadIdx.x;  // i = k*128 + o
    if (i >= 160 * 128) return;
    int k = i >> 7;
    float w = (k < 153) ? W_so[i] : 0.0f;
    short hh = f2bf(w);
    Whi[i] = hh;
    Wlo[i] = f2bf(w - bf2f(hh));
}

// ---------------------------------------------------------------------------
// Kernel 1: 16-way linked-list bucketing. 1 atomicExch + 1 coalesced store
// per edge = minimal fabric ops for a data-dependent scatter.
// ---------------------------------------------------------------------------
__global__ __launch_bounds__(256) void bucket_kernel(
    const int* __restrict__ row,
    int* __restrict__ head,
    int* __restrict__ nxt) {
    int e = blockIdx.x * 256 + threadIdx.x;
    if (e >= N_EDGES) return;
    int r = row[e];
    int prev = atomicExch(&head[r * NCHAIN + (e & (NCHAIN - 1))], e);
    nxt[e] = prev;
}

// ---------------------------------------------------------------------------
// Kernel 2: all per-node algebra. 16 nodes per 256-thread block.
// LDS diet keeps 8 blocks/CU possible (18.9 KB <= 20 KB/block):
//  - chain/gate partial reduces via __shfl_xor (16 chains of a node are 16
//    consecutive lanes of one wave) instead of LDS reduce arrays
//  - sigL unions onto poolL (dead after MFMA A-frag reads; barrier guards)
// NO min-waves clamp: round-2's __launch_bounds__(256,8) forced VGPR=32 and
// spilled the MFMA working set to scratch (+47 MB HBM writes). Default bounds
// landed 52 VGPR (<64 cliff) spill-free in round 1 -> 8 waves/SIMD naturally.
// ---------------------------------------------------------------------------
__global__ __launch_bounds__(256) void node_kernel(
    const float* __restrict__ s,
    const float* __restrict__ v,
    const float* __restrict__ frames,
    const float* __restrict__ W_vd,
    const float* __restrict__ W_vdf,
    const short* __restrict__ Whi,
    const short* __restrict__ Wlo,
    const float* __restrict__ b_so,
    const float* __restrict__ W_vu,
    const float* __restrict__ W_vosf,
    const float* __restrict__ b_vosf,
    const float* __restrict__ W_vuf,
    const int* __restrict__ head,
    const int* __restrict__ nxt,
    float* __restrict__ out0,
    float* __restrict__ out1)
{
    __shared__ __align__(16) float poolL[NPB][MSTR];  // phase<=2: merged rows; epilogue+: sigL[16][128]
    __shared__ float vL[NPB][48];
    __shared__ float vhL[NPB][3][16];
    __shared__ float FbarL[NPB][9];
    __shared__ float vdfL[NPB][9];
    __shared__ float gateL[NPB][12];

    float (*sigL)[128] = (float (*)[128])&poolL[0][0];

    const int t = threadIdx.x;
    const int base = blockIdx.x * NPB;
    const int nn = t >> 4, h = t & 15;
    const int n = base + nn;

    // ---- phase 0: issue head load first (latency overlaps staging), stage
    //      v,s; 256 walkers traverse the 16 sub-chains; butterfly reduce ----
    int e = head[(size_t)n * NCHAIN + h];

#pragma unroll
    for (int r = 0; r < 3; r++) vL[nn][h * 3 + r] = v[(size_t)n * 48 + h * 3 + r];
#pragma unroll
    for (int r = 0; r < 8; r++) poolL[nn][h * 8 + r] = s[(size_t)n * 128 + h * 8 + r];

    {
        float fs[10];
#pragma unroll
        for (int k = 0; k < 10; k++) fs[k] = 0.f;
        while (e >= 0) {
            int en = nxt[e];  // dependent load issues first; frame loads overlap it
            const float* f = frames + (size_t)e * 9;
            const f4u* fp = (const f4u*)f;
            f4u x = fp[0];
            f4u y = fp[1];
            float z8 = f[8];
            fs[0] += x.a; fs[1] += x.b; fs[2] += x.c; fs[3] += x.d;
            fs[4] += y.a; fs[5] += y.b; fs[6] += y.c; fs[7] += y.d;
            fs[8] += z8;
            fs[9] += 1.0f;
            e = en;
        }
        // butterfly across the node's 16 lanes (contiguous within the wave)
#pragma unroll
        for (int m = 1; m < 16; m <<= 1) {
#pragma unroll
            for (int k = 0; k < 10; k++) fs[k] += __shfl_xor(fs[k], m);
        }
        if (h < 9) {
            float inv = 1.0f / fmaxf(fs[9], 1.0f);
            FbarL[nn][h] = fs[h] * inv;
        }
    }
    __syncthreads();

    // ---- phase 1b: vh, vnorm, vdf ----
    {
        float vh0 = 0.f, vh1 = 0.f, vh2 = 0.f;
#pragma unroll
        for (int i = 0; i < 16; i++) {
            float w = W_vd[i * 16 + h];
            vh0 += vL[nn][i * 3 + 0] * w;
            vh1 += vL[nn][i * 3 + 1] * w;
            vh2 += vL[nn][i * 3 + 2] * w;
        }
        vhL[nn][0][h] = vh0; vhL[nn][1][h] = vh1; vhL[nn][2][h] = vh2;
        poolL[nn][128 + h] = sqrtf(vh0 * vh0 + vh1 * vh1 + vh2 * vh2 + EPSV);
        if (h < 3) {
            int cc = h;
#pragma unroll
            for (int j = 0; j < 3; j++) {
                float a = 0.f;
#pragma unroll
                for (int i = 0; i < 16; i++) a += vL[nn][i * 3 + j] * W_vdf[i * 3 + cc];
                vdfL[nn][j * 3 + cc] = a;
            }
        }
    }
    __syncthreads();

    // ---- phase 1c: sh + zero-pad merged[144..163] ----
    {
        if (h < 9) {
            int c = h / 3, i = h % 3;
            float a = 0.f;
#pragma unroll
            for (int j = 0; j < 3; j++) a += FbarL[nn][i * 3 + j] * vdfL[nn][j * 3 + c];
            poolL[nn][144 + h] = a;
        } else {
            poolL[nn][144 + h] = 0.0f;  // 153..159
        }
        if (h < 4) poolL[nn][160 + h] = 0.0f;  // stride pad
    }
    __syncthreads();

    // ---- phase 2: C[16x128] = merged[16x160] @ W_so via split-bf16 MFMA ----
    // wave w handles o in [32w, 32w+32): two 16x16 tiles, K-loop 5x32.
    // A-frag: A[m=lane&15][k=quad*8+j]; B-frag: B[k=quad*8+j][n=lane&15];
    // C/D: col=lane&15, row=quad*4+reg (m89/m91/m120-verified layouts).
    {
        const int w = t >> 6;
        const int lane = t & 63;
        const int quad = lane >> 4;
        const int col = lane & 15;
        f32x4 acc[2];
        acc[0] = (f32x4){0.f, 0.f, 0.f, 0.f};
        acc[1] = (f32x4){0.f, 0.f, 0.f, 0.f};
#pragma unroll
        for (int kk = 0; kk < 5; kk++) {
            const int krow = kk * 32 + quad * 8;
            const float* ap = &poolL[col][krow];
            float4 a0v = *(const float4*)ap;
            float4 a1v = *(const float4*)(ap + 4);
            float av[8] = {a0v.x, a0v.y, a0v.z, a0v.w, a1v.x, a1v.y, a1v.z, a1v.w};
            s16x8 ahi, alo;
#pragma unroll
            for (int j = 0; j < 8; j++) {
                short hh = f2bf(av[j]);
                ahi[j] = hh;
                alo[j] = f2bf(av[j] - bf2f(hh));
            }
#pragma unroll
            for (int t0 = 0; t0 < 2; t0++) {
                int o = w * 32 + t0 * 16 + col;
                s16x8 bhi, blo;
#pragma unroll
                for (int j = 0; j < 8; j++) {
                    bhi[j] = Whi[(krow + j) * 128 + o];
                    blo[j] = Wlo[(krow + j) * 128 + o];
                }
                acc[t0] = __builtin_amdgcn_mfma_f32_16x16x32_bf16(ahi, bhi, acc[t0], 0, 0, 0);
                acc[t0] = __builtin_amdgcn_mfma_f32_16x16x32_bf16(ahi, blo, acc[t0], 0, 0, 0);
                acc[t0] = __builtin_amdgcn_mfma_f32_16x16x32_bf16(alo, bhi, acc[t0], 0, 0, 0);
            }
        }
        __syncthreads();  // all A-frag reads of poolL done -> safe to overlay sigL
        // epilogue: bias, relu -> out0, sigmoid -> sigL (overlaid on poolL)
#pragma unroll
        for (int t0 = 0; t0 < 2; t0++) {
            int o = w * 32 + t0 * 16 + col;
            float bso = b_so[o];
#pragma unroll
            for (int r = 0; r < 4; r++) {
                int nl = quad * 4 + r;
                float val = acc[t0][r] + bso;
                out0[(size_t)(base + nl) * 128 + o] = fmaxf(val, 0.0f);
                sigL[nl][o] = sigmoidf_(val);
            }
        }
    }
    __syncthreads();

    // ---- gate = sigmoid(sr) @ W_vosf + b_vosf : partials + shfl butterfly ----
    {
        const float* sp = &sigL[nn][h * 8];
        float4 s0 = *(const float4*)sp;
        float4 s1 = *(const float4*)(sp + 4);
        float sv[8] = {s0.x, s0.y, s0.z, s0.w, s1.x, s1.y, s1.z, s1.w};
        float p[9];
#pragma unroll
        for (int k = 0; k < 9; k++) p[k] = 0.f;
#pragma unroll
        for (int i = 0; i < 8; i++) {
            int o = h * 8 + i;
#pragma unroll
            for (int k = 0; k < 9; k++) p[k] += sv[i] * W_vosf[o * 9 + k];
        }
#pragma unroll
        for (int m = 1; m < 16; m <<= 1) {
#pragma unroll
            for (int k = 0; k < 9; k++) p[k] += __shfl_xor(p[k], m);
        }
        if (h < 9) gateL[nn][h] = p[h] + b_vosf[h];
    }
    __syncthreads();

    // ---- phase 3: vector path ----
    {
        int o = h;  // VO index
        float gv[9];
#pragma unroll
        for (int i = 0; i < 3; i++)
#pragma unroll
            for (int kk = 0; kk < 3; kk++) {
                float a = 0.f;
#pragma unroll
                for (int j = 0; j < 3; j++) a += gateL[nn][j * 3 + i] * FbarL[nn][j * 3 + kk];
                gv[i * 3 + kk] = a;
            }
        float gvr[3];
#pragma unroll
        for (int kk = 0; kk < 3; kk++) {
            float a = 0.f;
#pragma unroll
            for (int i = 0; i < 3; i++) a += gv[i * 3 + kk] * W_vuf[i * 16 + o];
            gvr[kk] = a;
        }
        float gn2 = sqrtf(gvr[0] * gvr[0] + gvr[1] * gvr[1] + gvr[2] * gvr[2] + EPSV);
        float sg = sigmoidf_(gn2);
#pragma unroll
        for (int c = 0; c < 3; c++) {
            float a = 0.f;
#pragma unroll
            for (int h2 = 0; h2 < 16; h2++) a += vhL[nn][c][h2] * W_vu[h2 * 16 + o];
            out1[(size_t)n * 48 + o * 3 + c] = a * sg;
        }
    }
}

extern "C" void kernel_launch(void* const* d_in, const int* in_sizes, int n_in,
                              void* d_out, int out_size, void* d_ws, size_t ws_size,
                              hipStream_t stream) {
    const float* s      = (const float*)d_in[0];
    const float* v      = (const float*)d_in[1];
    const float* frames = (const float*)d_in[2];
    const float* W_vd   = (const float*)d_in[3];
    const float* W_vdf  = (const float*)d_in[4];
    const float* W_so   = (const float*)d_in[5];
    const float* b_so   = (const float*)d_in[6];
    const float* W_vu   = (const float*)d_in[7];
    const float* W_vosf = (const float*)d_in[8];
    const float* b_vosf = (const float*)d_in[9];
    const float* W_vuf  = (const float*)d_in[10];
    const int* edge_index = (const int*)d_in[11];
    // d_in[12] = node_inputs (assumed truthy, per reference)

    // ws: head[50K*16 int] | next[1.6M int] | Whi[160*128 s16] | Wlo[160*128 s16]
    const size_t head_b = (size_t)N_NODES * NCHAIN * sizeof(int);  // 3.2 MB
    const size_t next_b = (size_t)N_EDGES * sizeof(int);           // 6.4 MB
    int*   head = (int*)d_ws;
    int*   nxt  = (int*)((char*)d_ws + head_b);
    short* Whi  = (short*)((char*)d_ws + head_b + next_b);
    short* Wlo  = Whi + 160 * 128;
    float* out0 = (float*)d_out;
    float* out1 = out0 + (size_t)N_NODES * 128;

    hipMemsetAsync(head, 0xFF, head_b, stream);  // head[n][c] = -1
    prep_w_kernel<<<(160 * 128 + 255) / 256, 256, 0, stream>>>(W_so, Whi, Wlo);
    bucket_kernel<<<(N_EDGES + 255) / 256, 256, 0, stream>>>(edge_index, head, nxt);
    node_kernel<<<N_NODES / NPB, 256, 0, stream>>>(
        s, v, frames, W_vd, W_vdf, Whi, Wlo, b_so, W_vu, W_vosf, b_vosf, W_vuf,
        head, nxt, out0, out1);
}